// Round 22
// baseline (24.422 us; speedup 1.0000x reference)
//
#include <hip/hip_runtime.h>

namespace {

constexpr int IMGSZ = 224;
constexpr int IMG2  = IMGSZ * IMGSZ;   // 50176
// ws float layout: 16 pre-shifted v tables (gi*4+sh)*176, then 4 u tables gi*160
constexpr int UT_OFF = 16 * 176;       // 2816 floats

// Prep (replaces the memset node): zeroes out AND materializes the tables.
//   vtab[(gi*4+sh)*176 + i] = v[i-11-sh] (0 outside [0,KSZ)), v = krow/piv
//   utab[gi*160 + 16 + j]   = u[j]       (0 outside)
__global__ __launch_bounds__(256) void prep_kernel(
    const float* __restrict__ k0, const float* __restrict__ k1,
    const float* __restrict__ k2, const float* __restrict__ k3,
    float* __restrict__ ws, float* __restrict__ out, int out4_count) {
  const int gid = blockIdx.x * 256 + threadIdx.x;
  if (gid < out4_count) {
    reinterpret_cast<float4*>(out)[gid] = make_float4(0.f, 0.f, 0.f, 0.f);
  }
  const int bid = blockIdx.x;
  if (bid < 16) {               // v table for gi = bid>>2, sh = bid&3
    const int gi = bid >> 2, sh = bid & 3;
    const float* kp = (gi == 0) ? k0 : (gi == 1) ? k1 : (gi == 2) ? k2 : k3;
    const int KSZ = (gi == 0) ? 1 : (gi == 1) ? 12 : (gi == 2) ? 57 : 124;
    const int C0 = KSZ / 2;
    const float rpiv = 1.0f / kp[C0 * KSZ + C0];
    if (threadIdx.x < 176) {
      const int k = (int)threadIdx.x - 11 - sh;
      ws[bid * 176 + threadIdx.x] =
          (k >= 0 && k < KSZ) ? kp[C0 * KSZ + k] * rpiv : 0.f;
    }
  } else if (bid < 20) {        // u table for gi = bid-16
    const int gi = bid - 16;
    const float* kp = (gi == 0) ? k0 : (gi == 1) ? k1 : (gi == 2) ? k2 : k3;
    const int KSZ = (gi == 0) ? 1 : (gi == 1) ? 12 : (gi == 2) ? 57 : 124;
    const int C0 = KSZ / 2;
    if (threadIdx.x < 160) {
      const int j = (int)threadIdx.x - 16;
      ws[UT_OFF + gi * 160 + threadIdx.x] =
          (j >= 0 && j < KSZ) ? kp[j * KSZ + C0] : 0.f;
    }
  }
}

// Champion (23.9us: coalesced lane map + heavy-first + (128,4) + prep'd
// table copies + combined cross-wave epilogue) with ONE change: the load
// path is UNCONDITIONALLY BRANCHLESS. Key fact: col_a0 is 4-aligned and
// IMGSZ%4==0, so every aligned 4-col block is either fully inside or fully
// outside the image horizontally -> the per-element clamped-scalar edge
// path (taken per-lane-divergently by ~60% of G=135 crops) is unnecessary.
//   ok = (0 <= cbase <= IMGSZ-4); load float4s at (ok ? cbase : 0);
//   sj = (a+b+c) * (ok ? 1 : 0).
// Out-of-image blocks contribute 0 (reference zero-padding); out-of-crop
// in-image blocks are zeroed by the v-table.
// One block = (b, 16-row chunk of one glimpse): row = lane>>2,
// seg = wv*4 + (lane&3); each 4-lane group reads a contiguous 64B row
// segment (coalesced). H[row][ox] = sum_c S[row][c]*v[c-ox] via compile-
// time register window vs the LDS v-table (pre-shifted by sh = col0&3).
// Reduce 4 segs (shfl {2,1}) -> h_lds[wv] -> barrier -> combined vertical
// partial over (h0+h1) -> one atomicAdd per element (144/block).
// k = u v^T (rank-1 bicubic): u[r] = k[r][c0], v[c] = k[c0][c] / k[c0][c0].
template <int G>
__device__ void chunk_glimpse(
    int b, int gi, int ch,
    const float* __restrict__ img, const int* __restrict__ locs,
    const float* __restrict__ ws, float* __restrict__ out,
    float* __restrict__ vpad2, float* __restrict__ upad,
    float (*__restrict__ h_lds)[16][12]) {
  const int tid = threadIdx.x;
  const int lane = tid & 63;
  const int wv = tid >> 6;
  const int r0 = ch * 16;

  const int x = locs[2 * b];
  const int y = locs[2 * b + 1];
  const int row0 = x - G / 2 + r0;
  const int col0 = y - G / 2;
  const int sh = col0 & 3;                 // floor-mod 4 (works for negative)
  const int col_a0 = col0 - sh;            // image-aligned start (16B aligned)
  const int R = (G - r0) < 16 ? (G - r0) : 16;
  const float* imgb = img + (size_t)b * (3 * IMG2);

  // contiguous table copies from ws (prep'd): v = 44 float4, u = 40 float4
  if (lane < 44) {
    reinterpret_cast<float4*>(vpad2)[lane] =
        reinterpret_cast<const float4*>(ws + (gi * 4 + sh) * 176)[lane];
  }
  if (lane < 40) {
    reinterpret_cast<float4*>(upad)[lane] =
        reinterpret_cast<const float4*>(ws + UT_OFF + gi * 160)[lane];
  }

  constexpr int NCB2 = (G + 2) / 4 + 1;    // aligned 4-col blocks (covers sh<=3)
  const int row = lane >> 2;                  // 0..15
  const int seg = wv * 4 + (lane & 3);        // 0..7

  float acc[12];
  #pragma unroll
  for (int i = 0; i < 12; ++i) acc[i] = 0.f;

  const int grow = row0 + row;
  if (row < R && (unsigned)grow < (unsigned)IMGSZ) {
    const float* prow = imgb + grow * IMGSZ;
    const int cend = col0 + G;
    for (int cb = seg; cb < NCB2; cb += 8) {
      const int cbase = col_a0 + 4 * cb;
      if (cbase >= cend) break;
      // branchless: aligned block is fully in- or fully out-of-image
      const bool ok = (cbase >= 0) && (cbase <= IMGSZ - 4);
      const int cb2 = ok ? cbase : 0;
      const float m = ok ? 1.f : 0.f;
      const float4 a  = *reinterpret_cast<const float4*>(prow + cb2);
      const float4 b4 = *reinterpret_cast<const float4*>(prow + IMG2 + cb2);
      const float4 c4 = *reinterpret_cast<const float4*>(prow + 2 * IMG2 + cb2);
      float sj[4];
      sj[0] = (a.x + b4.x + c4.x) * m;
      sj[1] = (a.y + b4.y + c4.y) * m;
      sj[2] = (a.z + b4.z + c4.z) * m;
      sj[3] = (a.w + b4.w + c4.w) * m;
      float vv[16];
      #pragma unroll
      for (int q = 0; q < 4; ++q) {
        const float4 v4 = *reinterpret_cast<const float4*>(vpad2 + 4 * cb + 4 * q);
        vv[q * 4 + 0] = v4.x; vv[q * 4 + 1] = v4.y;
        vv[q * 4 + 2] = v4.z; vv[q * 4 + 3] = v4.w;
      }
      #pragma unroll
      for (int j = 0; j < 4; ++j) {
        #pragma unroll
        for (int ox = 0; ox < 12; ++ox) {
          acc[ox] += sj[j] * vv[11 + j - ox];   // = v[c_rel - ox], c_rel = 4cb+j-sh
        }
      }
    }
  }

  // reduce 4 segs within each 4-lane group (segs at lane strides of 1;
  // association (s0+s2)+(s1+s3) matches the old {32,16} order bitwise)
  #pragma unroll
  for (int ox = 0; ox < 12; ++ox) {
    acc[ox] += __shfl_down(acc[ox], 2, 64);
    acc[ox] += __shfl_down(acc[ox], 1, 64);
  }
  if ((lane & 3) == 0) {
    #pragma unroll
    for (int ox = 0; ox < 12; ++ox) h_lds[wv][lane >> 2][ox] = acc[ox];
  }
  __syncthreads();

  // combined vertical partial over both waves' H -> one atomic per element
  float* outp = out + ((size_t)b * 4 + gi) * 144;
  for (int e = tid; e < 144; e += 128) {
    const int oy = e / 12;
    const int ox = e - oy * 12;
    float s = 0.f;
    #pragma unroll
    for (int r = 0; r < 16; ++r) {
      s += upad[16 + r0 + r - oy] * (h_lds[0][r][ox] + h_lds[1][r][ox]);
    }
    atomicAdd(&outp[e], s);
  }
}

__global__ __launch_bounds__(128, 4) void glimpse_kernel(
    const float* __restrict__ img, const int* __restrict__ locs,
    const float* __restrict__ ws, float* __restrict__ out) {
  __shared__ __align__(16) float vpad2[2][176];
  __shared__ __align__(16) float upad[2][160];
  __shared__ __align__(16) float h_lds[2][16][12];
  const int bid = blockIdx.x;
  const int b = bid & 255;
  const int t = 16 - (bid >> 8);     // heavy-first: G=135 chunks dispatch first
  const int wv = threadIdx.x >> 6;
  if (t == 0) {
    chunk_glimpse<12 >(b, 0, 0,     img, locs, ws, out, vpad2[wv], upad[wv], h_lds);
  } else if (t < 3) {
    chunk_glimpse<23 >(b, 1, t - 1, img, locs, ws, out, vpad2[wv], upad[wv], h_lds);
  } else if (t < 8) {
    chunk_glimpse<68 >(b, 2, t - 3, img, locs, ws, out, vpad2[wv], upad[wv], h_lds);
  } else {
    chunk_glimpse<135>(b, 3, t - 8, img, locs, ws, out, vpad2[wv], upad[wv], h_lds);
  }
}

}  // namespace

extern "C" void kernel_launch(void* const* d_in, const int* in_sizes, int n_in,
                              void* d_out, int out_size, void* d_ws, size_t ws_size,
                              hipStream_t stream) {
  const float* img  = (const float*)d_in[0];
  const int*   locs = (const int*)d_in[1];
  const float* k0   = (const float*)d_in[2];
  const float* k1   = (const float*)d_in[3];
  const float* k2   = (const float*)d_in[4];
  const float* k3   = (const float*)d_in[5];
  float* ws  = (float*)d_ws;
  float* out = (float*)d_out;

  const int out4_count = out_size / 4;     // out_size floats, /4 per float4
  prep_kernel<<<256, 256, 0, stream>>>(k0, k1, k2, k3, ws, out, out4_count);
  glimpse_kernel<<<256 * 17, 128, 0, stream>>>(img, locs, ws, out);
}

// Round 23
// 23.947 us; speedup vs baseline: 1.0198x; 1.0198x over previous
//
#include <hip/hip_runtime.h>

namespace {

constexpr int IMGSZ = 224;
constexpr int IMG2  = IMGSZ * IMGSZ;   // 50176
// ws float layout: 16 pre-shifted v tables (gi*4+sh)*176, then 4 u tables gi*160
constexpr int UT_OFF = 16 * 176;       // 2816 floats

// Prep (replaces the memset node): zeroes out AND materializes the tables.
//   vtab[(gi*4+sh)*176 + i] = v[i-11-sh] (0 outside [0,KSZ)), v = krow/piv
//   utab[gi*160 + 16 + j]   = u[j]       (0 outside)
__global__ __launch_bounds__(256) void prep_kernel(
    const float* __restrict__ k0, const float* __restrict__ k1,
    const float* __restrict__ k2, const float* __restrict__ k3,
    float* __restrict__ ws, float* __restrict__ out, int out4_count) {
  const int gid = blockIdx.x * 256 + threadIdx.x;
  if (gid < out4_count) {
    reinterpret_cast<float4*>(out)[gid] = make_float4(0.f, 0.f, 0.f, 0.f);
  }
  const int bid = blockIdx.x;
  if (bid < 16) {               // v table for gi = bid>>2, sh = bid&3
    const int gi = bid >> 2, sh = bid & 3;
    const float* kp = (gi == 0) ? k0 : (gi == 1) ? k1 : (gi == 2) ? k2 : k3;
    const int KSZ = (gi == 0) ? 1 : (gi == 1) ? 12 : (gi == 2) ? 57 : 124;
    const int C0 = KSZ / 2;
    const float rpiv = 1.0f / kp[C0 * KSZ + C0];
    if (threadIdx.x < 176) {
      const int k = (int)threadIdx.x - 11 - sh;
      ws[bid * 176 + threadIdx.x] =
          (k >= 0 && k < KSZ) ? kp[C0 * KSZ + k] * rpiv : 0.f;
    }
  } else if (bid < 20) {        // u table for gi = bid-16
    const int gi = bid - 16;
    const float* kp = (gi == 0) ? k0 : (gi == 1) ? k1 : (gi == 2) ? k2 : k3;
    const int KSZ = (gi == 0) ? 1 : (gi == 1) ? 12 : (gi == 2) ? 57 : 124;
    const int C0 = KSZ / 2;
    if (threadIdx.x < 160) {
      const int j = (int)threadIdx.x - 16;
      ws[UT_OFF + gi * 160 + threadIdx.x] =
          (j >= 0 && j < KSZ) ? kp[j * KSZ + C0] : 0.f;
    }
  }
}

// CHAMPION (23.9us, reverted from R22's regression): coalesced lane map +
// heavy-first dispatch + (128,4) + prep'd contiguous table copies +
// combined cross-wave epilogue. One block = (b, 16-row chunk of one
// glimpse): row = lane>>2, seg = wv*4 + (lane&3); each 4-lane group reads a
// contiguous 64B row segment (coalesced image-aligned float4s,
// channel-summed; divergent clamped-scalar path only for edge crops).
// H[row][ox] = sum_c S[row][c]*v[c-ox] via compile-time register window
// against the LDS v-table (pre-shifted by sh = col0 & 3). Reduce 4 segs
// (shfl {2,1}) -> h_lds[wv] -> barrier -> combined vertical pass over
// (h0[r][ox]+h1[r][ox]) -> one atomicAdd per element (144/block).
// k = u v^T (rank-1 bicubic): u[r] = k[r][c0], v[c] = k[c0][c] / k[c0][c0].
template <int G>
__device__ void chunk_glimpse(
    int b, int gi, int ch,
    const float* __restrict__ img, const int* __restrict__ locs,
    const float* __restrict__ ws, float* __restrict__ out,
    float* __restrict__ vpad2, float* __restrict__ upad,
    float (*__restrict__ h_lds)[16][12]) {
  const int tid = threadIdx.x;
  const int lane = tid & 63;
  const int wv = tid >> 6;
  const int r0 = ch * 16;

  const int x = locs[2 * b];
  const int y = locs[2 * b + 1];
  const int row0 = x - G / 2 + r0;
  const int col0 = y - G / 2;
  const int sh = col0 & 3;                 // floor-mod 4 (works for negative)
  const int col_a0 = col0 - sh;            // image-aligned start (16B aligned)
  const int R = (G - r0) < 16 ? (G - r0) : 16;
  const float* imgb = img + (size_t)b * (3 * IMG2);

  // contiguous table copies from ws (prep'd): v = 44 float4, u = 40 float4
  if (lane < 44) {
    reinterpret_cast<float4*>(vpad2)[lane] =
        reinterpret_cast<const float4*>(ws + (gi * 4 + sh) * 176)[lane];
  }
  if (lane < 40) {
    reinterpret_cast<float4*>(upad)[lane] =
        reinterpret_cast<const float4*>(ws + UT_OFF + gi * 160)[lane];
  }

  constexpr int NCB2 = (G + 2) / 4 + 1;    // aligned 4-col blocks (covers sh<=3)
  const int row = lane >> 2;                  // 0..15
  const int seg = wv * 4 + (lane & 3);        // 0..7

  float acc[12];
  #pragma unroll
  for (int i = 0; i < 12; ++i) acc[i] = 0.f;

  const int grow = row0 + row;
  if (row < R && (unsigned)grow < (unsigned)IMGSZ) {
    const float* prow = imgb + grow * IMGSZ;
    const int cend = col0 + G;
    for (int cb = seg; cb < NCB2; cb += 8) {
      const int cbase = col_a0 + 4 * cb;
      if (cbase >= cend) break;
      float sj[4];
      if (cbase >= 0 && cbase <= IMGSZ - 4) {
        const float4 a  = *reinterpret_cast<const float4*>(prow + cbase);
        const float4 b4 = *reinterpret_cast<const float4*>(prow + IMG2 + cbase);
        const float4 c4 = *reinterpret_cast<const float4*>(prow + 2 * IMG2 + cbase);
        sj[0] = a.x + b4.x + c4.x;
        sj[1] = a.y + b4.y + c4.y;
        sj[2] = a.z + b4.z + c4.z;
        sj[3] = a.w + b4.w + c4.w;
      } else {
        #pragma unroll
        for (int j = 0; j < 4; ++j) {
          const int cc = cbase + j;
          sj[j] = ((unsigned)cc < (unsigned)IMGSZ)
                      ? prow[cc] + prow[IMG2 + cc] + prow[2 * IMG2 + cc]
                      : 0.f;
        }
      }
      float vv[16];
      #pragma unroll
      for (int q = 0; q < 4; ++q) {
        const float4 v4 = *reinterpret_cast<const float4*>(vpad2 + 4 * cb + 4 * q);
        vv[q * 4 + 0] = v4.x; vv[q * 4 + 1] = v4.y;
        vv[q * 4 + 2] = v4.z; vv[q * 4 + 3] = v4.w;
      }
      #pragma unroll
      for (int j = 0; j < 4; ++j) {
        #pragma unroll
        for (int ox = 0; ox < 12; ++ox) {
          acc[ox] += sj[j] * vv[11 + j - ox];   // = v[c_rel - ox], c_rel = 4cb+j-sh
        }
      }
    }
  }

  // reduce 4 segs within each 4-lane group (segs at lane strides of 1;
  // association (s0+s2)+(s1+s3) matches the old {32,16} order bitwise)
  #pragma unroll
  for (int ox = 0; ox < 12; ++ox) {
    acc[ox] += __shfl_down(acc[ox], 2, 64);
    acc[ox] += __shfl_down(acc[ox], 1, 64);
  }
  if ((lane & 3) == 0) {
    #pragma unroll
    for (int ox = 0; ox < 12; ++ox) h_lds[wv][lane >> 2][ox] = acc[ox];
  }
  __syncthreads();

  // combined vertical partial over both waves' H -> one atomic per element
  float* outp = out + ((size_t)b * 4 + gi) * 144;
  for (int e = tid; e < 144; e += 128) {
    const int oy = e / 12;
    const int ox = e - oy * 12;
    float s = 0.f;
    #pragma unroll
    for (int r = 0; r < 16; ++r) {
      s += upad[16 + r0 + r - oy] * (h_lds[0][r][ox] + h_lds[1][r][ox]);
    }
    atomicAdd(&outp[e], s);
  }
}

__global__ __launch_bounds__(128, 4) void glimpse_kernel(
    const float* __restrict__ img, const int* __restrict__ locs,
    const float* __restrict__ ws, float* __restrict__ out) {
  __shared__ __align__(16) float vpad2[2][176];
  __shared__ __align__(16) float upad[2][160];
  __shared__ __align__(16) float h_lds[2][16][12];
  const int bid = blockIdx.x;
  const int b = bid & 255;
  const int t = 16 - (bid >> 8);     // heavy-first: G=135 chunks dispatch first
  const int wv = threadIdx.x >> 6;
  if (t == 0) {
    chunk_glimpse<12 >(b, 0, 0,     img, locs, ws, out, vpad2[wv], upad[wv], h_lds);
  } else if (t < 3) {
    chunk_glimpse<23 >(b, 1, t - 1, img, locs, ws, out, vpad2[wv], upad[wv], h_lds);
  } else if (t < 8) {
    chunk_glimpse<68 >(b, 2, t - 3, img, locs, ws, out, vpad2[wv], upad[wv], h_lds);
  } else {
    chunk_glimpse<135>(b, 3, t - 8, img, locs, ws, out, vpad2[wv], upad[wv], h_lds);
  }
}

}  // namespace

extern "C" void kernel_launch(void* const* d_in, const int* in_sizes, int n_in,
                              void* d_out, int out_size, void* d_ws, size_t ws_size,
                              hipStream_t stream) {
  const float* img  = (const float*)d_in[0];
  const int*   locs = (const int*)d_in[1];
  const float* k0   = (const float*)d_in[2];
  const float* k1   = (const float*)d_in[3];
  const float* k2   = (const float*)d_in[4];
  const float* k3   = (const float*)d_in[5];
  float* ws  = (float*)d_ws;
  float* out = (float*)d_out;

  const int out4_count = out_size / 4;     // out_size floats, /4 per float4
  prep_kernel<<<256, 256, 0, stream>>>(k0, k1, k2, k3, ws, out, out4_count);
  glimpse_kernel<<<256 * 17, 128, 0, stream>>>(img, locs, ws, out);
}